// Round 12
// baseline (133.620 us; speedup 1.0000x reference)
//
#include <hip/hip_runtime.h>

// TwoTwoNet: rank-2 recurrence collapse, round 11.
// NEW: clip-bypass fast path. If |al|*max|d| + |be|*max|e| <= 1 then NO
// channel can saturate -> clip is identity -> the step is an exact 2x2
// linear map with precomputed dots:
//   q1' = al*P11 + be*P12, q2' = al*P21 + be*P22, out = al*O1 + be*O2
//   (P11=<d,g1>, P12=<e,g1>, P21=<d,g2>, P22=<e,g2>, O1=<d,wo>, O2=<e,wo>)
// Guard is wave-uniform (ballot==all -> scalar branch); slow path = verified
// R10 pass (tables + packed inner + DPP reduce). Exact either way.
// Masked channels are excluded from the maxes (their g1/g2/wo are 0).

typedef float f32x2 __attribute__((ext_vector_type(2)));

constexpr int Bc = 256;
constexpr int Tc = 512;
constexpr int CH = Tc / 64;   // 8 chunks of 64 steps

__device__ __forceinline__ float readlane_f(float v, int l) {
    return __int_as_float(__builtin_amdgcn_readlane(__float_as_int(v), l));
}

__device__ __forceinline__ f32x2 pk_fma(f32x2 a, f32x2 b, f32x2 c) {
    f32x2 d;
    asm("v_pk_fma_f32 %0, %1, %2, %3" : "=v"(d) : "v"(a), "v"(b), "v"(c));
    return d;
}
__device__ __forceinline__ f32x2 pk_mul(f32x2 a, f32x2 b) {
    f32x2 d;
    asm("v_pk_mul_f32 %0, %1, %2" : "=v"(d) : "v"(a), "v"(b));
    return d;
}

// 3 interleaved 64-lane sums via DPP; totals -> lane 63 -> SGPRs.
#define DPP3(lvl, msk)                                                                              \
        "v_add_f32_dpp %[a], %[a], %[a] " lvl " row_mask:" msk " bank_mask:0xf bound_ctrl:1\n\t"    \
        "v_add_f32_dpp %[b], %[b], %[b] " lvl " row_mask:" msk " bank_mask:0xf bound_ctrl:1\n\t"    \
        "v_add_f32_dpp %[c], %[c], %[c] " lvl " row_mask:" msk " bank_mask:0xf bound_ctrl:1\n\t"

#define WAVE_REDUCE3_READ(h1, h2, h3, s1, s2, s3)                                                   \
    asm("s_nop 1\n\t"                                                                               \
        DPP3("row_shr:1",   "0xf")                                                                  \
        DPP3("row_shr:2",   "0xf")                                                                  \
        DPP3("row_shr:4",   "0xf")                                                                  \
        DPP3("row_shr:8",   "0xf")                                                                  \
        DPP3("row_bcast:15","0xa")                                                                  \
        DPP3("row_bcast:31","0xc")                                                                  \
        "v_readlane_b32 %[x], %[a], 63\n\t"                                                         \
        "v_readlane_b32 %[y], %[b], 63\n\t"                                                         \
        "v_readlane_b32 %[z], %[c], 63"                                                             \
        : [a] "+v"(h1), [b] "+v"(h2), [c] "+v"(h3),                                                 \
          [x] "=s"(s1), [y] "=s"(s2), [z] "=s"(s3))

#define DECL_TBL(i) f32x2 d2_##i, e2_##i, g1_##i, g2_##i, wo_##i

#define INIT_TBL(i) do { \
    _Pragma("unroll") \
    for (int h = 0; h < 2; ++h) { \
        const int c = lane + 64 * (2 * (i) + h); \
        const float dv   = dec_orth[c]; \
        const float ev   = enc_orth[c]; \
        const float mv   = mask[c]; \
        const float encv = encoder[c]; \
        const float decv = decoder[c]; \
        const float s0v  = state0[c]; \
        const float mdv = mv * dv, mev = mv * ev; \
        d2_##i[h]  = dv;  e2_##i[h]  = ev; \
        const float g1v = fmaf(w00, mdv, w01 * mev); \
        const float g2v = fmaf(w10, mdv, w11 * mev); \
        const float wov = mv * decv; \
        g1_##i[h] = g1v;  g2_##i[h] = g2v;  wo_##i[h] = wov; \
        s0d += s0v * dv;  s0e += s0v * ev; \
        kd = fmaf(mv * encv, dv, kd); \
        ke = fmaf(mv * encv, ev, ke); \
        pd1 = fmaf(dv, g1v, pd1);  pe1 = fmaf(ev, g1v, pe1); \
        pd2 = fmaf(dv, g2v, pd2);  pe2 = fmaf(ev, g2v, pe2); \
        od  = fmaf(dv, wov, od);   oe  = fmaf(ev, wov, oe); \
        const float dabs = (mv != 0.f) ? fabsf(dv) : 0.f; \
        const float eabs = (mv != 0.f) ? fabsf(ev) : 0.f; \
        dm = fmaxf(dm, dabs);  em = fmaxf(em, eabs); \
    } \
} while (0)

// One channel pair: pk_mul + pk_fma (tt), 2x med3, 3x pk_fma (accumulate).
#define ACC_J(i) do { \
    f32x2 tt = pk_fma(b2, e2_##i, pk_mul(a2, d2_##i)); \
    f32x2 mm; \
    mm.x = __builtin_amdgcn_fmed3f(tt.x, -1.0f, 1.0f); \
    mm.y = __builtin_amdgcn_fmed3f(tt.y, -1.0f, 1.0f); \
    p1 = pk_fma(mm, g1_##i, p1); \
    p2 = pk_fma(mm, g2_##i, p2); \
    po = pk_fma(mm, wo_##i, po); \
} while (0)

#define ACC_J0(i) do { \
    f32x2 tt = pk_fma(b2, e2_##i, pk_mul(a2, d2_##i)); \
    f32x2 mm; \
    mm.x = __builtin_amdgcn_fmed3f(tt.x, -1.0f, 1.0f); \
    mm.y = __builtin_amdgcn_fmed3f(tt.y, -1.0f, 1.0f); \
    p1 = pk_mul(mm, g1_##i); \
    p2 = pk_mul(mm, g2_##i); \
    po = pk_mul(mm, wo_##i); \
} while (0)

__global__ __attribute__((amdgpu_waves_per_eu(1, 1))) __launch_bounds__(64)
void twotwonet_kernel(
    const float* __restrict__ x,        // [B, T]
    const float* __restrict__ state0,   // [n]
    const float* __restrict__ mask,     // [n]
    const float* __restrict__ w,        // [2,2]
    const float* __restrict__ dec_orth, // [n]
    const float* __restrict__ enc_orth, // [n]
    const float* __restrict__ decoder,  // [n]
    const float* __restrict__ encoder,  // [n]
    float* __restrict__ out)            // [B, T]
{
    const int b    = blockIdx.x;
    const int lane = threadIdx.x;   // 0..63

    const float w00 = w[0], w01 = w[1], w10 = w[2], w11 = w[3];

    DECL_TBL(0); DECL_TBL(1); DECL_TBL(2); DECL_TBL(3);
    DECL_TBL(4); DECL_TBL(5); DECL_TBL(6); DECL_TBL(7);

    float s0d = 0.f, s0e = 0.f, kd = 0.f, ke = 0.f;
    float pd1 = 0.f, pe1 = 0.f, pd2 = 0.f, pe2 = 0.f, od = 0.f, oe = 0.f;
    float dm = 0.f, em = 0.f;
    INIT_TBL(0); INIT_TBL(1); INIT_TBL(2); INIT_TBL(3);
    INIT_TBL(4); INIT_TBL(5); INIT_TBL(6); INIT_TBL(7);

    // cold-path init reduce (runs once)
#pragma unroll
    for (int m = 32; m >= 1; m >>= 1) {
        s0d += __shfl_xor(s0d, m, 64);
        s0e += __shfl_xor(s0e, m, 64);
        kd  += __shfl_xor(kd, m, 64);
        ke  += __shfl_xor(ke, m, 64);
        pd1 += __shfl_xor(pd1, m, 64);
        pe1 += __shfl_xor(pe1, m, 64);
        pd2 += __shfl_xor(pd2, m, 64);
        pe2 += __shfl_xor(pe2, m, 64);
        od  += __shfl_xor(od, m, 64);
        oe  += __shfl_xor(oe, m, 64);
        dm = fmaxf(dm, __shfl_xor(dm, m, 64));
        em = fmaxf(em, __shfl_xor(em, m, 64));
    }
    // P11=pd1, P12=pe1, P21=pd2, P22=pe2, O1=od, O2=oe; Dmax=dm, Emax=em

    const float A1 = fmaf(w00, kd, w01 * ke);   // x-coupling for alpha
    const float A2 = fmaf(w10, kd, w11 * ke);   // x-coupling for beta

    // Preload this batch's x row prescaled by A1/A2: al = q1 + xr1, etc.
    const float* xrow = x + (size_t)b * Tc;
    float xr1[CH], xr2[CH];
#pragma unroll
    for (int c = 0; c < CH; ++c) {
        const float xv = xrow[lane + 64 * c];
        xr1[c] = xv * A1;
        xr2[c] = xv * A2;
    }

    // Carried state (wave-uniform): q1 = w00*Sd + w01*Se, q2 = w10*Sd + w11*Se
    float q1 = fmaf(w00, s0d, w01 * s0e);
    float q2 = fmaf(w10, s0d, w11 * s0e);

#pragma unroll
    for (int c = 0; c < CH; ++c) {
        float obuf = 0.f;
#pragma unroll 2
        for (int t2 = 0; t2 < 64; ++t2) {
            const float al = q1 + readlane_f(xr1[c], t2);
            const float be = q2 + readlane_f(xr2[c], t2);

            float ro;
            // Saturation-impossible guard (wave-uniform scalar branch).
            const float chk = fmaf(fabsf(be), em, fabsf(al) * dm);
            if (__ballot(chk <= 1.0f) == ~0ull) {
                // clip is identity on every live channel -> exact linear step
                q1 = fmaf(be, pe1, al * pd1);
                q2 = fmaf(be, pe2, al * pd2);
                ro = fmaf(be, oe,  al * od);
            } else {
                const f32x2 a2 = {al, al};
                const f32x2 b2 = {be, be};
                f32x2 p1, p2, po;
                ACC_J0(0);
                ACC_J(1); ACC_J(2); ACC_J(3);
                ACC_J(4); ACC_J(5); ACC_J(6); ACC_J(7);

                float h1 = p1.x + p1.y;
                float h2 = p2.x + p2.y;
                float ho = po.x + po.y;

                float r1, r2, r3;
                WAVE_REDUCE3_READ(h1, h2, ho, r1, r2, r3);
                q1 = r1;
                q2 = r2;
                ro = r3;
            }

            obuf = (t2 == lane) ? ro : obuf;
        }
        out[(size_t)b * Tc + 64 * c + lane] = obuf;
    }
}

extern "C" void kernel_launch(void* const* d_in, const int* in_sizes, int n_in,
                              void* d_out, int out_size, void* d_ws, size_t ws_size,
                              hipStream_t stream) {
    const float* x        = (const float*)d_in[0];
    const float* state0   = (const float*)d_in[1];
    const float* mask     = (const float*)d_in[2];
    const float* w        = (const float*)d_in[3];
    const float* dec_orth = (const float*)d_in[4];
    const float* enc_orth = (const float*)d_in[5];
    const float* decoder  = (const float*)d_in[6];
    const float* encoder  = (const float*)d_in[7];
    float* out = (float*)d_out;

    twotwonet_kernel<<<dim3(Bc), dim3(64), 0, stream>>>(
        x, state0, mask, w, dec_orth, enc_orth, decoder, encoder, out);
}